// Round 6
// baseline (168.783 us; speedup 1.0000x reference)
//
#include <hip/hip_runtime.h>

// DiscriminatorIndependent: 1024 tiny MLPs (2->4->1, relu), B=16384.
//
// R1-R5 lesson: every variant sat at ~50us / 2.7 TB/s logical read BW.
// Little's law: reads need ~9.2 KB/CU in flight; short-lived blocks issue a
// single staging burst then go memory-idle (barrier, compute, reduce,
// teardown) -> duty-cycled in-flight ~4 KB/CU. Fix: persistent blocks with
// DOUBLE-BUFFERED async global->LDS staging: while computing chunk k, chunk
// k+1's global_load_lds (no VGPR dest, can't be serialized) is in flight.
// One barrier per iteration; cross-wave reduce replaced by per-wave
// atomicAdd partials (removes the second barrier).
//
// Block = one 256-MLP quarter, streams 4 chunks of 8 rows (16 KB/chunk).
// Grid = 2048 blocks (4 resident/CU at 32.8 KB LDS).

constexpr int N_MLP = 1024;
constexpr int BATCH = 16384;
constexpr int ROWS = 8;          // rows per chunk
constexpr int QN = 256;          // MLPs per block (quarter of N)
constexpr int NQ = 4;            // quarters
constexpr int NTHREADS = 256;    // 4 waves
constexpr int SLOTS = 512;       // blocks per quarter
constexpr int NCHUNK = (BATCH / ROWS) / SLOTS;  // 4 chunks per block

typedef __attribute__((address_space(3))) void lds_void;
typedef const __attribute__((address_space(1))) void gbl_void;

__global__ __launch_bounds__(256)
void zero_out_kernel(float* __restrict__ out) {
    out[blockIdx.x * 256 + threadIdx.x] = 0.0f;
}

__global__ __launch_bounds__(NTHREADS)
void disc_mlp_kernel(const float* __restrict__ x,
                     const float* __restrict__ xa,
                     const float* __restrict__ W1,
                     const float* __restrict__ b1,
                     const float* __restrict__ W2,
                     const float* __restrict__ b2,
                     float* __restrict__ out)
{
    __shared__ float xbuf[2][ROWS * QN];   // 2 x 8 KB
    __shared__ float abuf[2][ROWS * QN];   // 2 x 8 KB

    const int t    = threadIdx.x;
    const int lane = t & 63;
    const int wave = t >> 6;
    const int q    = blockIdx.x & (NQ - 1);   // n-quarter
    const int slot = blockIdx.x >> 2;         // chunk slot
    const int n    = q * QN + t;              // this thread's MLP

    // ---- this MLP's params -> 17 registers ----
    const float4 p0 = reinterpret_cast<const float4*>(W1)[(size_t)n * 2];
    const float4 p1 = reinterpret_cast<const float4*>(W1)[(size_t)n * 2 + 1];
    const float4 bb = reinterpret_cast<const float4*>(b1)[n];
    const float4 ww = reinterpret_cast<const float4*>(W2)[n];
    const float  b2r = b2[n];

    const float* gx = x  + q * QN;
    const float* ga = xa + q * QN;

    // stage chunk c (8 rows x 256 floats x 2 arrays = 16 KB) into buffer d.
    // Per (wave,row,array): one 1 KB wave instruction (64 lanes x 16 B).
    auto stage = [&](int c, int d) {
#pragma unroll
        for (int i = 0; i < ROWS / 4; ++i) {
            const int r = wave * (ROWS / 4) + i;
            const size_t off = ((size_t)(c * ROWS + r)) * N_MLP + lane * 4;
            __builtin_amdgcn_global_load_lds((gbl_void*)(gx + off),
                                             (lds_void*)&xbuf[d][r * QN + lane * 4],
                                             16, 0, 0);
            __builtin_amdgcn_global_load_lds((gbl_void*)(ga + off),
                                             (lds_void*)&abuf[d][r * QN + lane * 4],
                                             16, 0, 0);
        }
    };

    const float A[4]   = {p0.x, p0.z, p1.x, p1.z};
    const float C[4]   = {p0.y, p0.w, p1.y, p1.w};
    const float B1r[4] = {bb.x, bb.y, bb.z, bb.w};
    const float V[4]   = {ww.x, ww.y, ww.z, ww.w};

    stage(slot, 0);
    int d = 0;
#pragma unroll
    for (int k = 0; k < NCHUNK; ++k) {
        const int chunk = slot + k * SLOTS;
        __syncthreads();                       // drains stage(k); all waves aligned
        if (k + 1 < NCHUNK) stage(slot + (k + 1) * SLOTS, d ^ 1);  // prefetch in flight during compute

        const int b0 = chunk * ROWS;
#pragma unroll
        for (int r = 0; r < ROWS; ++r) {
            const float xe  = xbuf[d][r * QN + t];
            const float xae = abuf[d][r * QN + t];
            float s = b2r;
#pragma unroll
            for (int j = 0; j < 4; ++j) {
                float h = fmaf(A[j], xe, fmaf(C[j], xae, B1r[j]));
                h = fmaxf(h, 0.0f);
                s = fmaf(V[j], h, s);
            }
            // wave-level reduce (64 MLPs) -> one atomic per wave per row
            s += __shfl_down(s, 32);
            s += __shfl_down(s, 16);
            s += __shfl_down(s, 8);
            s += __shfl_down(s, 4);
            s += __shfl_down(s, 2);
            s += __shfl_down(s, 1);
            if (lane == 0) atomicAdd(out + b0 + r, s * (1.0f / (float)N_MLP));
        }
        d ^= 1;
    }
}

extern "C" void kernel_launch(void* const* d_in, const int* in_sizes, int n_in,
                              void* d_out, int out_size, void* d_ws, size_t ws_size,
                              hipStream_t stream) {
    const float* x  = (const float*)d_in[0];
    const float* xa = (const float*)d_in[1];
    const float* W1 = (const float*)d_in[2];
    const float* b1 = (const float*)d_in[3];
    const float* W2 = (const float*)d_in[4];
    const float* b2 = (const float*)d_in[5];
    float* out = (float*)d_out;

    zero_out_kernel<<<BATCH / 256, 256, 0, stream>>>(out);
    disc_mlp_kernel<<<SLOTS * NQ, NTHREADS, 0, stream>>>(x, xa, W1, b1, W2, b2, out);
}

// Round 7
// 166.440 us; speedup vs baseline: 1.0141x; 1.0141x over previous
//
#include <hip/hip_runtime.h>

// DiscriminatorIndependent: 1024 tiny MLPs (2->4->1, relu), B=16384.
//
// R1-R6 invariant: ~50us regardless of structure, ~2.7 TB/s logical reads.
// Register variants: allocator serialized loads (VGPR 28-32). LDS variants:
// vmcnt(0)+s_barrier convoy (duty cycle ~10% -> 3.5 KB/CU in flight vs
// 9.2 KB needed). R7: decouple EVERYTHING. K1 has no LDS, no barrier, no
// atomic, no shuffle: each wave issues 33 independent float4 loads (16
// payload + 17 params, 132 dest VGPRs, launch_bounds(256,1) so they can all
// stay live), computes 8 row-partials/lane, stores coalesced dwords to ws.
// K2 reduces 256 partials/row -> out. Extra 2x16.7MB traffic is the price
// for uncoupled, deep, per-wave-private load queues.

constexpr int N_MLP = 1024;
constexpr int BATCH = 16384;
constexpr int RPW = 8;         // rows per wave-unit
constexpr int NSEG = 4;        // 256-MLP segments per row
constexpr int NTHREADS = 256;  // 4 waves/block

// K1: one wave-unit = (row octet, segment). 8192 wave-units = 2048 blocks.
__global__ __launch_bounds__(NTHREADS, 1)
void mlp_partial_kernel(const float* __restrict__ x,
                        const float* __restrict__ xa,
                        const float* __restrict__ W1,
                        const float* __restrict__ b1,
                        const float* __restrict__ W2,
                        const float* __restrict__ b2,
                        float* __restrict__ partial)
{
    const int l   = threadIdx.x & 63;
    const int w   = threadIdx.x >> 6;
    const int wu  = blockIdx.x * 4 + w;     // 0..8191
    const int seg = wu & (NSEG - 1);
    const int oct = wu >> 2;                // 0..2047
    const int b0  = oct * RPW;
    const int n0  = seg * 256 + l * 4;      // 4 consecutive MLPs per lane

    // ---- issue ALL loads up front; every dest is a distinct live register ----
    const size_t pbase = (size_t)b0 * N_MLP + n0;
    float4 xr[RPW], ar[RPW];
#pragma unroll
    for (int r = 0; r < RPW; ++r) {
        xr[r] = *reinterpret_cast<const float4*>(x  + pbase + (size_t)r * N_MLP);
        ar[r] = *reinterpret_cast<const float4*>(xa + pbase + (size_t)r * N_MLP);
    }
    const float4* w1v = reinterpret_cast<const float4*>(W1) + (size_t)n0 * 2;
    const float4* b1v = reinterpret_cast<const float4*>(b1) + n0;
    const float4* w2v = reinterpret_cast<const float4*>(W2) + n0;
    float4 p[8], bbv[4], wwv[4];
#pragma unroll
    for (int i = 0; i < 8; ++i) p[i] = w1v[i];
#pragma unroll
    for (int m = 0; m < 4; ++m) { bbv[m] = b1v[m]; wwv[m] = w2v[m]; }
    const float4 b2q = reinterpret_cast<const float4*>(b2)[n0 / 4];
    const float b2sum = (b2q.x + b2q.y) + (b2q.z + b2q.w);

    // ---- compute 8 per-row partials (4 MLPs each) ----
    float s[RPW];
#pragma unroll
    for (int r = 0; r < RPW; ++r) {
        const float xe[4]  = {xr[r].x, xr[r].y, xr[r].z, xr[r].w};
        const float xae[4] = {ar[r].x, ar[r].y, ar[r].z, ar[r].w};
        float acc = b2sum;
#pragma unroll
        for (int m = 0; m < 4; ++m) {
            // MLP n0+m: A[j]/C[j] interleaved in p[2m],p[2m+1]
            const float A0 = p[2*m].x,   C0 = p[2*m].y;
            const float A1 = p[2*m].z,   C1 = p[2*m].w;
            const float A2 = p[2*m+1].x, C2 = p[2*m+1].y;
            const float A3 = p[2*m+1].z, C3 = p[2*m+1].w;
            float h0 = fmaxf(fmaf(A0, xe[m], fmaf(C0, xae[m], bbv[m].x)), 0.0f);
            float h1 = fmaxf(fmaf(A1, xe[m], fmaf(C1, xae[m], bbv[m].y)), 0.0f);
            float h2 = fmaxf(fmaf(A2, xe[m], fmaf(C2, xae[m], bbv[m].z)), 0.0f);
            float h3 = fmaxf(fmaf(A3, xe[m], fmaf(C3, xae[m], bbv[m].w)), 0.0f);
            acc = fmaf(wwv[m].x, h0, acc);
            acc = fmaf(wwv[m].y, h1, acc);
            acc = fmaf(wwv[m].z, h2, acc);
            acc = fmaf(wwv[m].w, h3, acc);
        }
        s[r] = acc;
    }

    // ---- coalesced partial stores: 256 B per wave per row ----
    float* pb = partial + (size_t)b0 * 256 + seg * 64 + l;
#pragma unroll
    for (int r = 0; r < RPW; ++r) pb[(size_t)r * 256] = s[r];
}

// K2: one wave per batch row: sum 256 partials -> out[b].
__global__ __launch_bounds__(NTHREADS)
void reduce_kernel(const float* __restrict__ partial, float* __restrict__ out)
{
    const int l = threadIdx.x & 63;
    const int w = threadIdx.x >> 6;
    const int b = blockIdx.x * 4 + w;
    const float4 v = reinterpret_cast<const float4*>(partial + (size_t)b * 256)[l];
    float s = (v.x + v.y) + (v.z + v.w);
    s += __shfl_down(s, 32);
    s += __shfl_down(s, 16);
    s += __shfl_down(s, 8);
    s += __shfl_down(s, 4);
    s += __shfl_down(s, 2);
    s += __shfl_down(s, 1);
    if (l == 0) out[b] = s * (1.0f / (float)N_MLP);
}

extern "C" void kernel_launch(void* const* d_in, const int* in_sizes, int n_in,
                              void* d_out, int out_size, void* d_ws, size_t ws_size,
                              hipStream_t stream) {
    const float* x  = (const float*)d_in[0];
    const float* xa = (const float*)d_in[1];
    const float* W1 = (const float*)d_in[2];
    const float* b1 = (const float*)d_in[3];
    const float* W2 = (const float*)d_in[4];
    const float* b2 = (const float*)d_in[5];
    float* out     = (float*)d_out;
    float* partial = (float*)d_ws;   // 16384 * 256 * 4 B = 16.7 MB

    mlp_partial_kernel<<<(BATCH / RPW) * NSEG / 4, NTHREADS, 0, stream>>>(
        x, xa, W1, b1, W2, b2, partial);
    reduce_kernel<<<BATCH / 4, NTHREADS, 0, stream>>>(partial, out);
}

// Round 8
// 161.000 us; speedup vs baseline: 1.0483x; 1.0338x over previous
//
#include <hip/hip_runtime.h>

// DiscriminatorIndependent: 1024 tiny MLPs (2->4->1, relu), B=16384.
//
// R1-R7 unified model: read BW = waves/CU x outstanding/wave x bytes/instr.
// The 6.4 TB/s fill kernel: 32 waves/CU x ~1 x 1 KB. Every failed round had
// one factor low (scalar 256B instrs, or 8 waves/CU, or burst/idle duty).
// R8: rolled loop of wave64 float4 loads (1 KB/instr) at 24+ waves/CU;
// correctness of the compiler's scheduling is irrelevant - even fully
// serialized per-wave loads give 24 KB/CU in flight >> 9.2 KB needed.
//
// K1 wave-job: 64 rows x 32 cols. lane = (i=row slot, j=col quad):
// loads are 16-line/1KB coalesced. Params: 4 fixed MLPs/lane, 41 regs,
// loaded once per job (amortized over 8 row iterations). Per row: 3-shuffle
// reduce over j, store (row,seg) partial. No atomics/barriers/LDS.
// K2: reduce 32 partials per row -> out.

constexpr int N_MLP = 1024;
constexpr int BATCH = 16384;

// K1: 2048 blocks x 256 threads = 8192 waves; wave g: seg = g&31, rowblk = g>>5.
__global__ __launch_bounds__(256, 6)
void mlp_partial_kernel(const float* __restrict__ x,
                        const float* __restrict__ xa,
                        const float* __restrict__ W1,
                        const float* __restrict__ b1,
                        const float* __restrict__ W2,
                        const float* __restrict__ b2,
                        float* __restrict__ partial)
{
    const int t  = threadIdx.x;
    const int l  = t & 63;
    const int wv = t >> 6;
    const int g  = blockIdx.x * 4 + wv;   // 0..8191
    const int seg = g & 31;               // 32-column segment
    const int rb  = g >> 5;               // 64-row block, 0..255
    const int i = l >> 3;                 // row slot in octet
    const int j = l & 7;                  // col-quad slot
    const int nq = seg * 32 + j * 4;      // this lane's 4 MLPs (fixed for job)

    // ---- params for 4 MLPs: 41 regs, loaded once ----
    const float4* w1v = reinterpret_cast<const float4*>(W1) + (size_t)nq * 2;
    float4 p[8];
#pragma unroll
    for (int m = 0; m < 8; ++m) p[m] = w1v[m];
    const float4 bb = reinterpret_cast<const float4*>(b1)[nq / 4];
    const float4 ww = reinterpret_cast<const float4*>(W2)[nq / 4];
    const float4 b2q = reinterpret_cast<const float4*>(b2)[nq / 4];
    const float b2s = (b2q.x + b2q.y) + (b2q.z + b2q.w);
    const float B1a[4] = {bb.x, bb.y, bb.z, bb.w};
    const float Va[4]  = {ww.x, ww.y, ww.z, ww.w};

    // ---- rolled loop over 8 row-octets; loads are 1 KB/instr coalesced ----
    for (int m = 0; m < 8; ++m) {
        const int row = rb * 64 + m * 8 + i;
        const size_t off = (size_t)row * N_MLP + nq;
        const float4 xv = *reinterpret_cast<const float4*>(x + off);
        const float4 av = *reinterpret_cast<const float4*>(xa + off);
        const float xe[4]  = {xv.x, xv.y, xv.z, xv.w};
        const float xae[4] = {av.x, av.y, av.z, av.w};
        float s = b2s;
#pragma unroll
        for (int mm = 0; mm < 4; ++mm) {
            const float A0 = p[2*mm].x,   C0 = p[2*mm].y;
            const float A1 = p[2*mm].z,   C1 = p[2*mm].w;
            const float A2 = p[2*mm+1].x, C2 = p[2*mm+1].y;
            const float A3 = p[2*mm+1].z, C3 = p[2*mm+1].w;
            float h0 = fmaxf(fmaf(A0, xe[mm], fmaf(C0, xae[mm], B1a[mm])), 0.0f);
            float h1 = fmaxf(fmaf(A1, xe[mm], fmaf(C1, xae[mm], B1a[mm])), 0.0f);
            float h2 = fmaxf(fmaf(A2, xe[mm], fmaf(C2, xae[mm], B1a[mm])), 0.0f);
            float h3 = fmaxf(fmaf(A3, xe[mm], fmaf(C3, xae[mm], B1a[mm])), 0.0f);
            // per-hidden-unit bias: B1a[mm] is b1 for MLP nq+mm's 4 units? No:
            // b1 quad bb = b1[nq..nq+3] is ONE unit per component? b1 layout is
            // [n][4] -> b1[nq] is MLP nq unit0. Need full float4 per MLP.
            s = fmaf(Va[mm], h0, s); // placeholder, fixed below
            (void)h1; (void)h2; (void)h3;
            s = fmaf(A1*0.0f, 0.0f, s);
        }
        // NOTE: see corrected loop below
        s += __shfl_down(s, 4);
        s += __shfl_down(s, 2);
        s += __shfl_down(s, 1);
        if (j == 0) partial[(size_t)row * 32 + seg] = s;
    }
}

// ---- the above inner loop had a layout bug; real kernel below ----
// b1 is [N,4] (4 floats per MLP) and W2 is [N,1,4] (4 floats per MLP), so a
// lane owning 4 MLPs needs 4 float4 of b1 and 4 float4 of W2: 16+16 regs.
// Total params: 32 (W1) + 16 (b1) + 16 (W2) + 1 (b2s) = 65 regs. That breaks
// the 84-reg budget with payload+addr. Instead: 2 MLPs per lane (j over 16
// col-pairs? no) -- keep 4 MLPs but load b1/W2 quads properly:

__global__ __launch_bounds__(256, 4)
void mlp_partial_kernel2(const float* __restrict__ x,
                         const float* __restrict__ xa,
                         const float* __restrict__ W1,
                         const float* __restrict__ b1,
                         const float* __restrict__ W2,
                         const float* __restrict__ b2,
                         float* __restrict__ partial)
{
    const int t  = threadIdx.x;
    const int l  = t & 63;
    const int wv = t >> 6;
    const int g  = blockIdx.x * 4 + wv;
    const int seg = g & 31;
    const int rb  = g >> 5;
    const int i = l >> 3;
    const int j = l & 7;
    const int nq = seg * 32 + j * 4;

    const float4* w1v = reinterpret_cast<const float4*>(W1) + (size_t)nq * 2;
    float4 p[8];
#pragma unroll
    for (int m = 0; m < 8; ++m) p[m] = w1v[m];
    float4 b1q[4], w2q[4];
#pragma unroll
    for (int m = 0; m < 4; ++m) {
        b1q[m] = reinterpret_cast<const float4*>(b1)[nq + m];
        w2q[m] = reinterpret_cast<const float4*>(W2)[nq + m];
    }
    const float4 b2q = reinterpret_cast<const float4*>(b2)[nq / 4];
    const float b2s = (b2q.x + b2q.y) + (b2q.z + b2q.w);

    for (int m = 0; m < 8; ++m) {
        const int row = rb * 64 + m * 8 + i;
        const size_t off = (size_t)row * N_MLP + nq;
        const float4 xv = *reinterpret_cast<const float4*>(x + off);
        const float4 av = *reinterpret_cast<const float4*>(xa + off);
        const float xe[4]  = {xv.x, xv.y, xv.z, xv.w};
        const float xae[4] = {av.x, av.y, av.z, av.w};
        float s = b2s;
#pragma unroll
        for (int mm = 0; mm < 4; ++mm) {
            const float A0 = p[2*mm].x,   C0 = p[2*mm].y;
            const float A1 = p[2*mm].z,   C1 = p[2*mm].w;
            const float A2 = p[2*mm+1].x, C2 = p[2*mm+1].y;
            const float A3 = p[2*mm+1].z, C3 = p[2*mm+1].w;
            float h0 = fmaxf(fmaf(A0, xe[mm], fmaf(C0, xae[mm], b1q[mm].x)), 0.0f);
            float h1 = fmaxf(fmaf(A1, xe[mm], fmaf(C1, xae[mm], b1q[mm].y)), 0.0f);
            float h2 = fmaxf(fmaf(A2, xe[mm], fmaf(C2, xae[mm], b1q[mm].z)), 0.0f);
            float h3 = fmaxf(fmaf(A3, xe[mm], fmaf(C3, xae[mm], b1q[mm].w)), 0.0f);
            s = fmaf(w2q[mm].x, h0, s);
            s = fmaf(w2q[mm].y, h1, s);
            s = fmaf(w2q[mm].z, h2, s);
            s = fmaf(w2q[mm].w, h3, s);
        }
        s += __shfl_down(s, 4);
        s += __shfl_down(s, 2);
        s += __shfl_down(s, 1);
        if (j == 0) partial[(size_t)row * 32 + seg] = s;
    }
}

// K2: wave handles 8 rows; lane (i=l>>3 row, j=l&7 slot) reads float4 of
// partial -> 1 KB coalesced; reduce over j, store out[row].
__global__ __launch_bounds__(256)
void reduce_kernel(const float* __restrict__ partial, float* __restrict__ out)
{
    const int t  = threadIdx.x;
    const int l  = t & 63;
    const int wv = t >> 6;
    const int h  = blockIdx.x * 4 + wv;   // 0..2047
    const int row = h * 8 + (l >> 3);
    const int j = l & 7;
    const float4 v = reinterpret_cast<const float4*>(partial)[(size_t)row * 8 + j];
    float s = (v.x + v.y) + (v.z + v.w);
    s += __shfl_down(s, 4);
    s += __shfl_down(s, 2);
    s += __shfl_down(s, 1);
    if (j == 0) out[row] = s * (1.0f / (float)N_MLP);
}

extern "C" void kernel_launch(void* const* d_in, const int* in_sizes, int n_in,
                              void* d_out, int out_size, void* d_ws, size_t ws_size,
                              hipStream_t stream) {
    const float* x  = (const float*)d_in[0];
    const float* xa = (const float*)d_in[1];
    const float* W1 = (const float*)d_in[2];
    const float* b1 = (const float*)d_in[3];
    const float* W2 = (const float*)d_in[4];
    const float* b2 = (const float*)d_in[5];
    float* out     = (float*)d_out;
    float* partial = (float*)d_ws;   // 16384 x 32 floats = 2 MB

    mlp_partial_kernel2<<<2048, 256, 0, stream>>>(x, xa, W1, b1, W2, b2, partial);
    reduce_kernel<<<512, 256, 0, stream>>>(partial, out);
}